// Round 1
// baseline (3436.525 us; speedup 1.0000x reference)
//
#include <hip/hip_runtime.h>
#include <math.h>

#define SS 2048
#define HH 2048
#define HQ 16
#define HKV 4
#define GG 4
#define DD 128
#define KS 32
#define KSTRIDE 16
#define NCMP 127
#define NBLK 16
#define TOPK 8
#define WINSZ 512
#define TQ 16

// ---------------- RoPE tables (llama3-style scaled inv freq) ----------------
__global__ void rope_tab(float* __restrict__ cost, float* __restrict__ sint) {
    int s = blockIdx.x;
    int i = threadIdx.x; // 0..63
    double inv = pow(500000.0, -(double)i / 64.0);
    double wav = 6.283185307179586476925286766559 / inv;
    double inv_s;
    if (wav > 8192.0) inv_s = inv / 8.0;
    else if (wav < 2048.0) inv_s = inv;
    else {
        double sm = (8192.0 / wav - 1.0) / 3.0;
        inv_s = (1.0 - sm) * inv / 8.0 + sm * inv;
    }
    float ang = (float)s * (float)inv_s; // reference computes angle in f32
    cost[s * 64 + i] = cosf(ang);
    sint[s * 64 + i] = sinf(ang);
}

__global__ void rope_apply(float* __restrict__ x, const float* __restrict__ cost,
                           const float* __restrict__ sint, int nh) {
    int s = blockIdx.x, h = blockIdx.y, i = threadIdx.x; // i<64
    float* p = x + ((size_t)s * nh + h) * DD;
    float c = cost[s * 64 + i], sn = sint[s * 64 + i];
    float x1 = p[i], x2 = p[i + 64];
    p[i] = x1 * c - x2 * sn;
    p[i + 64] = x2 * c + x1 * sn;
}

__global__ void sigmoid_k(float* __restrict__ x, int n) {
    int i = blockIdx.x * 256 + threadIdx.x;
    if (i < n) x[i] = 1.f / (1.f + __expf(-x[i]));
}

// ---------------- generic f32 GEMM: C[M,N] = A[M,K] @ B[K,N] ----------------
// 128x128 tile, BK=16, 256 threads, 8x8 microtile. M,K multiples of 128/16; N guarded.
__global__ __launch_bounds__(256) void gemm_f32(const float* __restrict__ A,
                                                const float* __restrict__ B,
                                                float* __restrict__ C,
                                                int M, int N, int K) {
    __shared__ float As[16][129];
    __shared__ float Bs[16][129];
    int t = threadIdx.x;
    int tx = t & 15, ty = t >> 4;
    int bm = blockIdx.y * 128, bn = blockIdx.x * 128;
    float acc[8][8] = {};
    for (int k0 = 0; k0 < K; k0 += 16) {
#pragma unroll
        for (int i = 0; i < 8; ++i) {
            int flat = i * 256 + t;
            int m = flat >> 4, kk = flat & 15;
            As[kk][m] = A[(size_t)(bm + m) * K + k0 + kk];
        }
#pragma unroll
        for (int i = 0; i < 8; ++i) {
            int flat = i * 256 + t;
            int r = flat >> 7, cc = flat & 127;
            int col = bn + cc;
            Bs[r][cc] = (col < N) ? B[(size_t)(k0 + r) * N + col] : 0.f;
        }
        __syncthreads();
#pragma unroll
        for (int kk = 0; kk < 16; ++kk) {
            float a[8], b[8];
#pragma unroll
            for (int i = 0; i < 8; ++i) a[i] = As[kk][ty * 8 + i];
#pragma unroll
            for (int j = 0; j < 8; ++j) b[j] = Bs[kk][tx + 16 * j];
#pragma unroll
            for (int i = 0; i < 8; ++i)
#pragma unroll
                for (int j = 0; j < 8; ++j)
                    acc[i][j] = fmaf(a[i], b[j], acc[i][j]);
        }
        __syncthreads();
    }
    for (int i = 0; i < 8; ++i) {
        int m = bm + ty * 8 + i;
        for (int j = 0; j < 8; ++j) {
            int n = bn + tx + 16 * j;
            if (n < N) C[(size_t)m * N + n] = acc[i][j];
        }
    }
}

// ---------------- compressed K/V build ----------------
// ck[h][n][d] = sum_f k[n*16 + f/128][h][f%128] * Wck[h][f][d]
__global__ __launch_bounds__(128) void cmp_kv(const float* __restrict__ k,
                                              const float* __restrict__ v,
                                              const float* __restrict__ Wck,
                                              const float* __restrict__ Wcv,
                                              float* __restrict__ ck,
                                              float* __restrict__ cv) {
    int n = blockIdx.x, h = blockIdx.y, t = threadIdx.x; // t<128
    __shared__ float w[KS * DD];
    for (int r = 0; r < KS; ++r)
        w[r * DD + t] = k[((size_t)(n * KSTRIDE + r) * HKV + h) * DD + t];
    __syncthreads();
    {
        float acc = 0.f;
        const float* Wp = Wck + (size_t)h * KS * DD * DD + t;
        for (int f = 0; f < KS * DD; ++f) acc = fmaf(w[f], Wp[(size_t)f * DD], acc);
        ck[((size_t)h * NCMP + n) * DD + t] = acc;
    }
    __syncthreads();
    for (int r = 0; r < KS; ++r)
        w[r * DD + t] = v[((size_t)(n * KSTRIDE + r) * HKV + h) * DD + t];
    __syncthreads();
    {
        float acc = 0.f;
        const float* Wp = Wcv + (size_t)h * KS * DD * DD + t;
        for (int f = 0; f < KS * DD; ++f) acc = fmaf(w[f], Wp[(size_t)f * DD], acc);
        cv[((size_t)h * NCMP + n) * DD + t] = acc;
    }
}

// ---------------- compressed attention + block scores + top-8 ----------------
__global__ __launch_bounds__(128) void cmp_attn(const float* __restrict__ q,
                                                const float* __restrict__ ck,
                                                const float* __restrict__ cv,
                                                const float* __restrict__ gate,
                                                float* __restrict__ o_acc,
                                                unsigned int* __restrict__ sel) {
    int s = blockIdx.x, h = blockIdx.y, t = threadIdx.x; // t<128
    __shared__ float qs[GG][DD];
    __shared__ float p[GG][NCMP + 1];
    __shared__ float red[128];
    __shared__ float bsc[NBLK];
    const float scale = 0.08838834764831845f;
    for (int g = 0; g < GG; ++g)
        qs[g][t] = q[((size_t)s * HQ + h * GG + g) * DD + t] * scale;
    __syncthreads();
    int nv = (s >= 31) ? ((s - 31) >> 4) + 1 : 0; // number of valid compressed keys
    int n = t;
    bool act = (n < nv);
    float dots[GG] = {0.f, 0.f, 0.f, 0.f};
    if (act) {
        const float* ckp = ck + ((size_t)h * NCMP + n) * DD;
        for (int d = 0; d < DD; ++d) {
            float kv = ckp[d];
#pragma unroll
            for (int g = 0; g < GG; ++g) dots[g] = fmaf(qs[g][d], kv, dots[g]);
        }
    }
    for (int g = 0; g < GG; ++g) {
        float val = act ? dots[g] : -1e30f;
        red[t] = val; __syncthreads();
        for (int off = 64; off > 0; off >>= 1) {
            if (t < off) red[t] = fmaxf(red[t], red[t + off]);
            __syncthreads();
        }
        float m = red[0]; __syncthreads();
        float e = act ? __expf(dots[g] - m) : 0.f;
        red[t] = e; __syncthreads();
        for (int off = 64; off > 0; off >>= 1) {
            if (t < off) red[t] += red[t + off];
            __syncthreads();
        }
        float l = red[0]; __syncthreads();
        p[g][t] = (nv > 0) ? e / l : 0.f;
        __syncthreads();
    }
    // o_cmp, gated by gate[...,0]
    {
        int d = t;
        float accs[GG] = {0.f, 0.f, 0.f, 0.f};
        const float* cvp = cv + (size_t)h * NCMP * DD + d;
        for (int nn = 0; nn < nv; ++nn) {
            float cvv = cvp[(size_t)nn * DD];
#pragma unroll
            for (int g = 0; g < GG; ++g) accs[g] = fmaf(p[g][nn], cvv, accs[g]);
        }
        for (int g = 0; g < GG; ++g) {
            float g0 = gate[((size_t)s * HQ + h * GG + g) * 3 + 0];
            o_acc[((size_t)s * HQ + h * GG + g) * DD + d] = g0 * accs[g];
        }
    }
    // block scores
    if (t < NBLK) {
        float b = 0.f;
        for (int g = 0; g < GG; ++g)
            for (int j = 0; j < 8; ++j) b += p[g][t * 8 + j]; // p[.][127]==0
        bsc[t] = b;
    }
    __syncthreads();
    if (t == 0) {
        int qblk = s >> 7;
        float sc[NBLK];
        for (int b = 0; b < NBLK; ++b) {
            bool forced = (b == 0) || (b <= qblk && b > qblk - 2);
            sc[b] = bsc[b] + (forced ? 1e9f : 0.f); // f32 add: forced -> exactly 1e9f
        }
        unsigned int mask = 0;
        for (int it = 0; it < TOPK; ++it) {
            int arg = 0; float best = sc[0];
            for (int b = 1; b < NBLK; ++b)
                if (sc[b] > best) { best = sc[b]; arg = b; } // strict >: lowest idx on tie
            mask |= 1u << arg;
            sc[arg] = -1e38f;
        }
        sel[s * HKV + h] = mask;
    }
}

// ---------------- selected + windowed attention (flash style) ----------------
__global__ __launch_bounds__(256) void sel_win(const float* __restrict__ q,
                                               const float* __restrict__ k,
                                               const float* __restrict__ v,
                                               const float* __restrict__ gate,
                                               const unsigned int* __restrict__ sel,
                                               float* __restrict__ o_acc) {
    int s0 = blockIdx.x * TQ;
    int hq = blockIdx.y;
    int h = hq >> 2;
    int t = threadIdx.x;
    int r = t >> 4, c = t & 15;
    __shared__ float qs[TQ][132];
    __shared__ float kvs[64][132];
    __shared__ float ps[2][TQ][66];
    __shared__ unsigned int sm[TQ];
    const float scale = 0.08838834764831845f;
#pragma unroll
    for (int i = 0; i < 8; ++i) {
        int flat = i * 256 + t;
        int rr = flat >> 7, dd = flat & 127;
        qs[rr][dd] = q[((size_t)(s0 + rr) * HQ + hq) * DD + dd] * scale;
    }
    if (t < TQ) sm[t] = sel[(s0 + t) * HKV + h];
    __syncthreads();
    int sr = s0 + r;
    unsigned int mymask = sm[r];
    unsigned int orMask = 0;
    for (int i = 0; i < TQ; ++i) orMask |= sm[i];
    float m_sel = -1e30f, l_sel = 0.f, m_win = -1e30f, l_win = 0.f;
    float os[8] = {}, ow[8] = {};

    for (int kb = 0; kb < NBLK && kb * 128 <= s0 + TQ - 1; ++kb) {
        int kst = kb * 128;
        bool needSel = (orMask >> kb) & 1u;
        bool selbit = needSel && ((mymask >> kb) & 1u);
        for (int half = 0; half < 2; ++half) {
            int hst = kst + half * 64;
            if (hst > s0 + TQ - 1) break;
            bool hWin = (hst + 63 >= s0 - (WINSZ - 1));
            if (!(needSel || hWin)) continue;
            // stage K rows [hst, hst+64)
#pragma unroll
            for (int i = 0; i < 32; ++i) {
                int flat = i * 256 + t;
                int key = flat >> 7, dd = flat & 127;
                kvs[key][dd] = k[((size_t)(hst + key) * HKV + h) * DD + dd];
            }
            __syncthreads();
            float raw[4];
#pragma unroll
            for (int j = 0; j < 4; ++j) {
                int kl = c + 16 * j;
                float acc = 0.f;
                for (int d = 0; d < DD; ++d) acc = fmaf(qs[r][d], kvs[kl][d], acc);
                raw[j] = acc;
            }
            // ---- sel plane ----
            if (needSel) {
                float ev[4]; float mx = -1e30f;
#pragma unroll
                for (int j = 0; j < 4; ++j) {
                    int kg = hst + c + 16 * j;
                    bool valid = selbit && (kg <= sr);
                    ev[j] = valid ? raw[j] : -1e30f;
                    mx = fmaxf(mx, ev[j]);
                }
                for (int off = 8; off > 0; off >>= 1) mx = fmaxf(mx, __shfl_xor(mx, off, 16));
                if (mx > -1e29f) {
                    float newm = fmaxf(m_sel, mx);
                    float corr = __expf(m_sel - newm);
                    float lsum = 0.f;
#pragma unroll
                    for (int j = 0; j < 4; ++j) {
                        float pv = (ev[j] > -1e29f) ? __expf(ev[j] - newm) : 0.f;
                        ps[0][r][c + 16 * j] = pv;
                        lsum += pv;
                    }
                    for (int off = 8; off > 0; off >>= 1) lsum += __shfl_xor(lsum, off, 16);
                    l_sel = l_sel * corr + lsum;
#pragma unroll
                    for (int j = 0; j < 8; ++j) os[j] *= corr;
                    m_sel = newm;
                } else {
#pragma unroll
                    for (int j = 0; j < 4; ++j) ps[0][r][c + 16 * j] = 0.f;
                }
            }
            // ---- win plane ----
            if (hWin) {
                float ev[4]; float mx = -1e30f;
#pragma unroll
                for (int j = 0; j < 4; ++j) {
                    int kg = hst + c + 16 * j;
                    bool valid = (kg <= sr) && (kg > sr - WINSZ);
                    ev[j] = valid ? raw[j] : -1e30f;
                    mx = fmaxf(mx, ev[j]);
                }
                for (int off = 8; off > 0; off >>= 1) mx = fmaxf(mx, __shfl_xor(mx, off, 16));
                if (mx > -1e29f) {
                    float newm = fmaxf(m_win, mx);
                    float corr = __expf(m_win - newm);
                    float lsum = 0.f;
#pragma unroll
                    for (int j = 0; j < 4; ++j) {
                        float pv = (ev[j] > -1e29f) ? __expf(ev[j] - newm) : 0.f;
                        ps[1][r][c + 16 * j] = pv;
                        lsum += pv;
                    }
                    for (int off = 8; off > 0; off >>= 1) lsum += __shfl_xor(lsum, off, 16);
                    l_win = l_win * corr + lsum;
#pragma unroll
                    for (int j = 0; j < 8; ++j) ow[j] *= corr;
                    m_win = newm;
                } else {
#pragma unroll
                    for (int j = 0; j < 4; ++j) ps[1][r][c + 16 * j] = 0.f;
                }
            }
            __syncthreads();
            // stage V rows [hst, hst+64)
#pragma unroll
            for (int i = 0; i < 32; ++i) {
                int flat = i * 256 + t;
                int key = flat >> 7, dd = flat & 127;
                kvs[key][dd] = v[((size_t)(hst + key) * HKV + h) * DD + dd];
            }
            __syncthreads();
            if (needSel) {
                for (int key = 0; key < 64; ++key) {
                    float pv = ps[0][r][key];
#pragma unroll
                    for (int j = 0; j < 8; ++j) os[j] = fmaf(pv, kvs[key][c + 16 * j], os[j]);
                }
            }
            if (hWin) {
                for (int key = 0; key < 64; ++key) {
                    float pv = ps[1][r][key];
#pragma unroll
                    for (int j = 0; j < 8; ++j) ow[j] = fmaf(pv, kvs[key][c + 16 * j], ow[j]);
                }
            }
            __syncthreads();
        }
    }
    float g1 = gate[((size_t)sr * HQ + hq) * 3 + 1];
    float g2 = gate[((size_t)sr * HQ + hq) * 3 + 2];
    float invls = (l_sel > 0.f) ? 1.f / l_sel : 0.f;
    float invlw = (l_win > 0.f) ? 1.f / l_win : 0.f;
#pragma unroll
    for (int j = 0; j < 8; ++j) {
        int dd = c + 16 * j;
        size_t idx = ((size_t)sr * HQ + hq) * DD + dd;
        o_acc[idx] += g1 * os[j] * invls + g2 * ow[j] * invlw;
    }
}

extern "C" void kernel_launch(void* const* d_in, const int* in_sizes, int n_in,
                              void* d_out, int out_size, void* d_ws, size_t ws_size,
                              hipStream_t stream) {
    const float* x   = (const float*)d_in[0];
    const float* Wq  = (const float*)d_in[1];
    const float* Wk  = (const float*)d_in[2];
    const float* Wv  = (const float*)d_in[3];
    const float* Wo  = (const float*)d_in[4];
    const float* Wg  = (const float*)d_in[5];
    const float* Wck = (const float*)d_in[6];
    const float* Wcv = (const float*)d_in[7];
    float* out = (float*)d_out;
    char* w = (char*)d_ws;
    float* qb   = (float*)(w + 0);         // S*HQ*D f32   = 16 MiB
    float* kb   = (float*)(w + 16777216);  // S*HKV*D      = 4 MiB
    float* vb   = (float*)(w + 20971520);  // S*HKV*D      = 4 MiB
    float* g3   = (float*)(w + 25165824);  // S*HQ*3
    float* ckb  = (float*)(w + 25559040);  // HKV*127*128
    float* cvb  = (float*)(w + 25819136);
    unsigned int* selb = (unsigned int*)(w + 26079232); // S*HKV
    float* cost = (float*)(w + 26112000);  // S*64
    float* sint = (float*)(w + 26636288);
    float* oacc = (float*)(w + 27160576);  // S*HQ*D = 16 MiB  (end ~44 MiB)

    hipLaunchKernelGGL(rope_tab, dim3(SS), dim3(64), 0, stream, cost, sint);
    hipLaunchKernelGGL(gemm_f32, dim3(16, 16), dim3(256), 0, stream, x, Wq, qb, 2048, 2048, 2048);
    hipLaunchKernelGGL(gemm_f32, dim3(4, 16),  dim3(256), 0, stream, x, Wk, kb, 2048, 512, 2048);
    hipLaunchKernelGGL(gemm_f32, dim3(4, 16),  dim3(256), 0, stream, x, Wv, vb, 2048, 512, 2048);
    hipLaunchKernelGGL(gemm_f32, dim3(1, 16),  dim3(256), 0, stream, x, Wg, g3, 2048, 48, 2048);
    hipLaunchKernelGGL(rope_apply, dim3(SS, HQ),  dim3(64), 0, stream, qb, cost, sint, HQ);
    hipLaunchKernelGGL(rope_apply, dim3(SS, HKV), dim3(64), 0, stream, kb, cost, sint, HKV);
    hipLaunchKernelGGL(sigmoid_k, dim3((SS * HQ * 3 + 255) / 256), dim3(256), 0, stream, g3, SS * HQ * 3);
    hipLaunchKernelGGL(cmp_kv, dim3(NCMP, HKV), dim3(128), 0, stream, kb, vb, Wck, Wcv, ckb, cvb);
    hipLaunchKernelGGL(cmp_attn, dim3(SS, HKV), dim3(128), 0, stream, qb, ckb, cvb, g3, oacc, selb);
    hipLaunchKernelGGL(sel_win, dim3(SS / TQ, HQ), dim3(256), 0, stream, qb, kb, vb, g3, selb, oacc);
    hipLaunchKernelGGL(gemm_f32, dim3(16, 16), dim3(256), 0, stream, oacc, Wo, out, 2048, 2048, 2048);
}

// Round 2
// 1554.390 us; speedup vs baseline: 2.2109x; 2.2109x over previous
//
#include <hip/hip_runtime.h>
#include <math.h>

#define SS 2048
#define HH 2048
#define HQ 16
#define HKV 4
#define GG 4
#define DD 128
#define KS 32
#define KSTRIDE 16
#define NCMP 127
#define NBLK 16
#define TOPK 8
#define WINSZ 512
#define TQ 16

typedef unsigned short u16;
typedef __bf16 bf16x8 __attribute__((ext_vector_type(8)));
typedef float f32x4 __attribute__((ext_vector_type(4)));

__device__ __forceinline__ u16 f2bf(float f) {
    __bf16 b = (__bf16)f;
    return __builtin_bit_cast(u16, b);
}

// ---------------- RoPE tables (llama3-style scaled inv freq) ----------------
__global__ void rope_tab(float* __restrict__ cost, float* __restrict__ sint) {
    int s = blockIdx.x;
    int i = threadIdx.x; // 0..63
    double inv = pow(500000.0, -(double)i / 64.0);
    double wav = 6.283185307179586476925286766559 / inv;
    double inv_s;
    if (wav > 8192.0) inv_s = inv / 8.0;
    else if (wav < 2048.0) inv_s = inv;
    else {
        double sm = (8192.0 / wav - 1.0) / 3.0;
        inv_s = (1.0 - sm) * inv / 8.0 + sm * inv;
    }
    float ang = (float)s * (float)inv_s; // reference computes angle in f32
    cost[s * 64 + i] = cosf(ang);
    sint[s * 64 + i] = sinf(ang);
}

__global__ void rope_apply(float* __restrict__ x, const float* __restrict__ cost,
                           const float* __restrict__ sint, int nh) {
    int s = blockIdx.x, h = blockIdx.y, i = threadIdx.x; // i<64
    float* p = x + ((size_t)s * nh + h) * DD;
    float c = cost[s * 64 + i], sn = sint[s * 64 + i];
    float x1 = p[i], x2 = p[i + 64];
    p[i] = x1 * c - x2 * sn;
    p[i + 64] = x2 * c + x1 * sn;
}

__global__ void sigmoid_k(float* __restrict__ x, int n) {
    int i = blockIdx.x * 256 + threadIdx.x;
    if (i < n) x[i] = 1.f / (1.f + __expf(-x[i]));
}

// ---------------- f32 -> bf16 flat convert (vec4) ----------------
__global__ void conv_bf16(const float* __restrict__ in, u16* __restrict__ out, int n4) {
    int i = blockIdx.x * 256 + threadIdx.x;
    if (i < n4) {
        float4 v = ((const float4*)in)[i];
        ushort4 o;
        o.x = f2bf(v.x); o.y = f2bf(v.y); o.z = f2bf(v.z); o.w = f2bf(v.w);
        ((ushort4*)out)[i] = o;
    }
}

// ---------------- convert + transpose: W[K][N] f32 -> Bt[Npad][K] bf16 ----------------
__global__ __launch_bounds__(256) void convT(const float* __restrict__ W, u16* __restrict__ Bt,
                                             int K, int N, int Npad) {
    __shared__ float tile[32][33];
    int bk = blockIdx.x * 32, bn = blockIdx.y * 32;
    int tx = threadIdx.x & 31, ty = threadIdx.x >> 5; // ty 0..7
#pragma unroll
    for (int i = 0; i < 32; i += 8) {
        int k = bk + ty + i, n = bn + tx;
        tile[ty + i][tx] = (n < N) ? W[(size_t)k * N + n] : 0.f;
    }
    __syncthreads();
#pragma unroll
    for (int i = 0; i < 32; i += 8) {
        int n = bn + ty + i, k = bk + tx;
        if (n < Npad) Bt[(size_t)n * K + k] = f2bf(tile[tx][ty + i]);
    }
}

// ---------------- bf16 MFMA GEMM: C[M,N] = A[M,K] @ Bt[N,K]^T ----------------
// 128x128 tile, BK=64, 256 threads (4 waves, 2x2), 16x16x32 MFMA, XOR-swizzled LDS.
__device__ __forceinline__ void gload16(const void* g, void* l) {
    __builtin_amdgcn_global_load_lds((const __attribute__((address_space(1))) void*)g,
                                     (__attribute__((address_space(3))) void*)l, 16, 0, 0);
}

__global__ __launch_bounds__(256) void gemm_mfma(const u16* __restrict__ A,
                                                 const u16* __restrict__ Bt,
                                                 float* __restrict__ C,
                                                 int M, int N, int K) {
    __shared__ __align__(16) u16 Asm[128 * 64];
    __shared__ __align__(16) u16 Bsm[128 * 64];
    int t = threadIdx.x;
    int lane = t & 63;
    int w = t >> 6;
    int wm = w >> 1, wn = w & 1;
    int bm = blockIdx.y * 128, bn = blockIdx.x * 128;
    int lr = lane & 15, hi = lane >> 4;

    f32x4 acc[4][4] = {};
    // staging coords for this thread (4 chunks per buffer)
    int cflat0 = t;            // + i*256
    for (int k0 = 0; k0 < K; k0 += 64) {
        if (k0) __syncthreads();           // prev compute done before overwrite
#pragma unroll
        for (int i = 0; i < 4; ++i) {
            int cflat = i * 256 + cflat0;      // 16B chunk id 0..1023
            int m = cflat >> 3;                // row in tile
            int g = cflat & 7;                 // stored k-group
            int gl = g ^ (m & 7);              // global k-group (swizzle)
            unsigned lofs = (unsigned)((i * 256 + (t & ~63)) * 16);
            gload16(A + (size_t)(bm + m) * K + k0 + gl * 8, (char*)Asm + lofs);
            gload16(Bt + (size_t)(bn + m) * K + k0 + gl * 8, (char*)Bsm + lofs);
        }
        __syncthreads();                   // staging visible (vmcnt drained by barrier)
#pragma unroll
        for (int kk = 0; kk < 2; ++kk) {
            bf16x8 af[4], bf[4];
#pragma unroll
            for (int mi = 0; mi < 4; ++mi) {
                int row = wm * 64 + mi * 16 + lr;
                int g = (kk * 4 + hi) ^ (row & 7);
                af[mi] = *reinterpret_cast<const bf16x8*>(&Asm[row * 64 + g * 8]);
            }
#pragma unroll
            for (int ni = 0; ni < 4; ++ni) {
                int row = wn * 64 + ni * 16 + lr;
                int g = (kk * 4 + hi) ^ (row & 7);
                bf[ni] = *reinterpret_cast<const bf16x8*>(&Bsm[row * 64 + g * 8]);
            }
#pragma unroll
            for (int mi = 0; mi < 4; ++mi)
#pragma unroll
                for (int ni = 0; ni < 4; ++ni)
                    acc[mi][ni] = __builtin_amdgcn_mfma_f32_16x16x32_bf16(af[mi], bf[ni], acc[mi][ni], 0, 0, 0);
        }
    }
#pragma unroll
    for (int mi = 0; mi < 4; ++mi) {
#pragma unroll
        for (int ni = 0; ni < 4; ++ni) {
            int col = bn + wn * 64 + ni * 16 + lr;
            if (col < N) {
#pragma unroll
                for (int r = 0; r < 4; ++r) {
                    int row = bm + wm * 64 + mi * 16 + hi * 4 + r;
                    C[(size_t)row * N + col] = acc[mi][ni][r];
                }
            }
        }
    }
}

// ---------------- compressed K/V build ----------------
__global__ __launch_bounds__(128) void cmp_kv(const float* __restrict__ k,
                                              const float* __restrict__ v,
                                              const float* __restrict__ Wck,
                                              const float* __restrict__ Wcv,
                                              float* __restrict__ ck,
                                              float* __restrict__ cv) {
    int n = blockIdx.x, h = blockIdx.y, t = threadIdx.x; // t<128
    __shared__ float w[KS * DD];
    for (int r = 0; r < KS; ++r)
        w[r * DD + t] = k[((size_t)(n * KSTRIDE + r) * HKV + h) * DD + t];
    __syncthreads();
    {
        float acc = 0.f;
        const float* Wp = Wck + (size_t)h * KS * DD * DD + t;
        for (int f = 0; f < KS * DD; ++f) acc = fmaf(w[f], Wp[(size_t)f * DD], acc);
        ck[((size_t)h * NCMP + n) * DD + t] = acc;
    }
    __syncthreads();
    for (int r = 0; r < KS; ++r)
        w[r * DD + t] = v[((size_t)(n * KSTRIDE + r) * HKV + h) * DD + t];
    __syncthreads();
    {
        float acc = 0.f;
        const float* Wp = Wcv + (size_t)h * KS * DD * DD + t;
        for (int f = 0; f < KS * DD; ++f) acc = fmaf(w[f], Wp[(size_t)f * DD], acc);
        cv[((size_t)h * NCMP + n) * DD + t] = acc;
    }
}

// ---------------- compressed attention + block scores + top-8 ----------------
__global__ __launch_bounds__(128) void cmp_attn(const float* __restrict__ q,
                                                const float* __restrict__ ck,
                                                const float* __restrict__ cv,
                                                const float* __restrict__ gate,
                                                float* __restrict__ o_acc,
                                                unsigned int* __restrict__ sel) {
    int s = blockIdx.x, h = blockIdx.y, t = threadIdx.x; // t<128
    __shared__ float qs[GG][DD];
    __shared__ float p[GG][NCMP + 1];
    __shared__ float red[128];
    __shared__ float bsc[NBLK];
    const float scale = 0.08838834764831845f;
    for (int g = 0; g < GG; ++g)
        qs[g][t] = q[((size_t)s * HQ + h * GG + g) * DD + t] * scale;
    __syncthreads();
    int nv = (s >= 31) ? ((s - 31) >> 4) + 1 : 0; // number of valid compressed keys
    int n = t;
    bool act = (n < nv);
    float dots[GG] = {0.f, 0.f, 0.f, 0.f};
    if (act) {
        const float* ckp = ck + ((size_t)h * NCMP + n) * DD;
        for (int d = 0; d < DD; ++d) {
            float kv = ckp[d];
#pragma unroll
            for (int g = 0; g < GG; ++g) dots[g] = fmaf(qs[g][d], kv, dots[g]);
        }
    }
    for (int g = 0; g < GG; ++g) {
        float val = act ? dots[g] : -1e30f;
        red[t] = val; __syncthreads();
        for (int off = 64; off > 0; off >>= 1) {
            if (t < off) red[t] = fmaxf(red[t], red[t + off]);
            __syncthreads();
        }
        float m = red[0]; __syncthreads();
        float e = act ? __expf(dots[g] - m) : 0.f;
        red[t] = e; __syncthreads();
        for (int off = 64; off > 0; off >>= 1) {
            if (t < off) red[t] += red[t + off];
            __syncthreads();
        }
        float l = red[0]; __syncthreads();
        p[g][t] = (nv > 0) ? e / l : 0.f;
        __syncthreads();
    }
    // o_cmp, gated by gate[...,0]
    {
        int d = t;
        float accs[GG] = {0.f, 0.f, 0.f, 0.f};
        const float* cvp = cv + (size_t)h * NCMP * DD + d;
        for (int nn = 0; nn < nv; ++nn) {
            float cvv = cvp[(size_t)nn * DD];
#pragma unroll
            for (int g = 0; g < GG; ++g) accs[g] = fmaf(p[g][nn], cvv, accs[g]);
        }
        for (int g = 0; g < GG; ++g) {
            float g0 = gate[((size_t)s * HQ + h * GG + g) * 3 + 0];
            o_acc[((size_t)s * HQ + h * GG + g) * DD + d] = g0 * accs[g];
        }
    }
    // block scores
    if (t < NBLK) {
        float b = 0.f;
        for (int g = 0; g < GG; ++g)
            for (int j = 0; j < 8; ++j) b += p[g][t * 8 + j]; // p[.][127]==0
        bsc[t] = b;
    }
    __syncthreads();
    if (t == 0) {
        int qblk = s >> 7;
        float sc[NBLK];
        for (int b = 0; b < NBLK; ++b) {
            bool forced = (b == 0) || (b <= qblk && b > qblk - 2);
            sc[b] = bsc[b] + (forced ? 1e9f : 0.f); // f32 add: forced -> exactly 1e9f
        }
        unsigned int mask = 0;
        for (int it = 0; it < TOPK; ++it) {
            int arg = 0; float best = sc[0];
            for (int b = 1; b < NBLK; ++b)
                if (sc[b] > best) { best = sc[b]; arg = b; } // strict >: lowest idx on tie
            mask |= 1u << arg;
            sc[arg] = -1e38f;
        }
        sel[s * HKV + h] = mask;
    }
}

// ---------------- selected + windowed attention (flash style) ----------------
__global__ __launch_bounds__(256) void sel_win(const float* __restrict__ q,
                                               const float* __restrict__ k,
                                               const float* __restrict__ v,
                                               const float* __restrict__ gate,
                                               const unsigned int* __restrict__ sel,
                                               float* __restrict__ o_acc) {
    int s0 = blockIdx.x * TQ;
    int hq = blockIdx.y;
    int h = hq >> 2;
    int t = threadIdx.x;
    int r = t >> 4, c = t & 15;
    __shared__ float qs[TQ][132];
    __shared__ float kvs[64][132];
    __shared__ float ps[2][TQ][66];
    __shared__ unsigned int sm[TQ];
    const float scale = 0.08838834764831845f;
#pragma unroll
    for (int i = 0; i < 8; ++i) {
        int flat = i * 256 + t;
        int rr = flat >> 7, dd = flat & 127;
        qs[rr][dd] = q[((size_t)(s0 + rr) * HQ + hq) * DD + dd] * scale;
    }
    if (t < TQ) sm[t] = sel[(s0 + t) * HKV + h];
    __syncthreads();
    int sr = s0 + r;
    unsigned int mymask = sm[r];
    unsigned int orMask = 0;
    for (int i = 0; i < TQ; ++i) orMask |= sm[i];
    float m_sel = -1e30f, l_sel = 0.f, m_win = -1e30f, l_win = 0.f;
    float os[8] = {}, ow[8] = {};

    for (int kb = 0; kb < NBLK && kb * 128 <= s0 + TQ - 1; ++kb) {
        int kst = kb * 128;
        bool needSel = (orMask >> kb) & 1u;
        bool selbit = needSel && ((mymask >> kb) & 1u);
        for (int half = 0; half < 2; ++half) {
            int hst = kst + half * 64;
            if (hst > s0 + TQ - 1) break;
            bool hWin = (hst + 63 >= s0 - (WINSZ - 1));
            if (!(needSel || hWin)) continue;
            // stage K rows [hst, hst+64)
#pragma unroll
            for (int i = 0; i < 32; ++i) {
                int flat = i * 256 + t;
                int key = flat >> 7, dd = flat & 127;
                kvs[key][dd] = k[((size_t)(hst + key) * HKV + h) * DD + dd];
            }
            __syncthreads();
            float raw[4];
#pragma unroll
            for (int j = 0; j < 4; ++j) {
                int kl = c + 16 * j;
                float acc = 0.f;
                for (int d = 0; d < DD; ++d) acc = fmaf(qs[r][d], kvs[kl][d], acc);
                raw[j] = acc;
            }
            // ---- sel plane ----
            if (needSel) {
                float ev[4]; float mx = -1e30f;
#pragma unroll
                for (int j = 0; j < 4; ++j) {
                    int kg = hst + c + 16 * j;
                    bool valid = selbit && (kg <= sr);
                    ev[j] = valid ? raw[j] : -1e30f;
                    mx = fmaxf(mx, ev[j]);
                }
                for (int off = 8; off > 0; off >>= 1) mx = fmaxf(mx, __shfl_xor(mx, off, 16));
                if (mx > -1e29f) {
                    float newm = fmaxf(m_sel, mx);
                    float corr = __expf(m_sel - newm);
                    float lsum = 0.f;
#pragma unroll
                    for (int j = 0; j < 4; ++j) {
                        float pv = (ev[j] > -1e29f) ? __expf(ev[j] - newm) : 0.f;
                        ps[0][r][c + 16 * j] = pv;
                        lsum += pv;
                    }
                    for (int off = 8; off > 0; off >>= 1) lsum += __shfl_xor(lsum, off, 16);
                    l_sel = l_sel * corr + lsum;
#pragma unroll
                    for (int j = 0; j < 8; ++j) os[j] *= corr;
                    m_sel = newm;
                } else {
#pragma unroll
                    for (int j = 0; j < 4; ++j) ps[0][r][c + 16 * j] = 0.f;
                }
            }
            // ---- win plane ----
            if (hWin) {
                float ev[4]; float mx = -1e30f;
#pragma unroll
                for (int j = 0; j < 4; ++j) {
                    int kg = hst + c + 16 * j;
                    bool valid = (kg <= sr) && (kg > sr - WINSZ);
                    ev[j] = valid ? raw[j] : -1e30f;
                    mx = fmaxf(mx, ev[j]);
                }
                for (int off = 8; off > 0; off >>= 1) mx = fmaxf(mx, __shfl_xor(mx, off, 16));
                if (mx > -1e29f) {
                    float newm = fmaxf(m_win, mx);
                    float corr = __expf(m_win - newm);
                    float lsum = 0.f;
#pragma unroll
                    for (int j = 0; j < 4; ++j) {
                        float pv = (ev[j] > -1e29f) ? __expf(ev[j] - newm) : 0.f;
                        ps[1][r][c + 16 * j] = pv;
                        lsum += pv;
                    }
                    for (int off = 8; off > 0; off >>= 1) lsum += __shfl_xor(lsum, off, 16);
                    l_win = l_win * corr + lsum;
#pragma unroll
                    for (int j = 0; j < 8; ++j) ow[j] *= corr;
                    m_win = newm;
                } else {
#pragma unroll
                    for (int j = 0; j < 4; ++j) ps[1][r][c + 16 * j] = 0.f;
                }
            }
            __syncthreads();
            // stage V rows [hst, hst+64)
#pragma unroll
            for (int i = 0; i < 32; ++i) {
                int flat = i * 256 + t;
                int key = flat >> 7, dd = flat & 127;
                kvs[key][dd] = v[((size_t)(hst + key) * HKV + h) * DD + dd];
            }
            __syncthreads();
            if (needSel) {
                for (int key = 0; key < 64; ++key) {
                    float pv = ps[0][r][key];
#pragma unroll
                    for (int j = 0; j < 8; ++j) os[j] = fmaf(pv, kvs[key][c + 16 * j], os[j]);
                }
            }
            if (hWin) {
                for (int key = 0; key < 64; ++key) {
                    float pv = ps[1][r][key];
#pragma unroll
                    for (int j = 0; j < 8; ++j) ow[j] = fmaf(pv, kvs[key][c + 16 * j], ow[j]);
                }
            }
            __syncthreads();
        }
    }
    float g1 = gate[((size_t)sr * HQ + hq) * 3 + 1];
    float g2 = gate[((size_t)sr * HQ + hq) * 3 + 2];
    float invls = (l_sel > 0.f) ? 1.f / l_sel : 0.f;
    float invlw = (l_win > 0.f) ? 1.f / l_win : 0.f;
#pragma unroll
    for (int j = 0; j < 8; ++j) {
        int dd = c + 16 * j;
        size_t idx = ((size_t)sr * HQ + hq) * DD + dd;
        o_acc[idx] += g1 * os[j] * invls + g2 * ow[j] * invlw;
    }
}

extern "C" void kernel_launch(void* const* d_in, const int* in_sizes, int n_in,
                              void* d_out, int out_size, void* d_ws, size_t ws_size,
                              hipStream_t stream) {
    const float* x   = (const float*)d_in[0];
    const float* Wq  = (const float*)d_in[1];
    const float* Wk  = (const float*)d_in[2];
    const float* Wv  = (const float*)d_in[3];
    const float* Wo  = (const float*)d_in[4];
    const float* Wg  = (const float*)d_in[5];
    const float* Wck = (const float*)d_in[6];
    const float* Wcv = (const float*)d_in[7];
    float* out = (float*)d_out;
    char* w = (char*)d_ws;
    float* qb   = (float*)(w + 0);          // 16 MiB
    float* kb   = (float*)(w + 16777216);   // 4 MiB
    float* vb   = (float*)(w + 20971520);   // 4 MiB
    float* g3   = (float*)(w + 25165824);
    float* ckb  = (float*)(w + 25559040);
    float* cvb  = (float*)(w + 25819136);
    unsigned int* selb = (unsigned int*)(w + 26079232);
    float* cost = (float*)(w + 26112000);
    float* sint = (float*)(w + 26636288);
    float* oacc = (float*)(w + 27160576);   // 16 MiB
    u16* xb     = (u16*)(w + 43937792);     // 8 MiB
    u16* oaccb  = (u16*)(w + 52326400);     // 8 MiB
    u16* Wq_t   = (u16*)(w + 60715008);     // 8 MiB
    u16* Wo_t   = (u16*)(w + 69103616);     // 8 MiB
    u16* Wk_t   = (u16*)(w + 77492224);     // 2 MiB
    u16* Wv_t   = (u16*)(w + 79589376);     // 2 MiB
    u16* Wg_t   = (u16*)(w + 81686528);     // 0.5 MiB

    hipLaunchKernelGGL(rope_tab, dim3(SS), dim3(64), 0, stream, cost, sint);
    // converts
    hipLaunchKernelGGL(conv_bf16, dim3(4096), dim3(256), 0, stream, x, xb, SS * HH / 4);
    hipLaunchKernelGGL(convT, dim3(64, 64), dim3(256), 0, stream, Wq, Wq_t, HH, 2048, 2048);
    hipLaunchKernelGGL(convT, dim3(64, 16), dim3(256), 0, stream, Wk, Wk_t, HH, 512, 512);
    hipLaunchKernelGGL(convT, dim3(64, 16), dim3(256), 0, stream, Wv, Wv_t, HH, 512, 512);
    hipLaunchKernelGGL(convT, dim3(64, 4),  dim3(256), 0, stream, Wg, Wg_t, HH, 48, 128);
    hipLaunchKernelGGL(convT, dim3(64, 64), dim3(256), 0, stream, Wo, Wo_t, HQ * DD, 2048, 2048);
    // projections (bf16 MFMA)
    hipLaunchKernelGGL(gemm_mfma, dim3(16, 16), dim3(256), 0, stream, xb, Wq_t, qb, 2048, 2048, 2048);
    hipLaunchKernelGGL(gemm_mfma, dim3(4, 16),  dim3(256), 0, stream, xb, Wk_t, kb, 2048, 512, 2048);
    hipLaunchKernelGGL(gemm_mfma, dim3(4, 16),  dim3(256), 0, stream, xb, Wv_t, vb, 2048, 512, 2048);
    hipLaunchKernelGGL(gemm_mfma, dim3(1, 16),  dim3(256), 0, stream, xb, Wg_t, g3, 2048, 48, 2048);
    hipLaunchKernelGGL(rope_apply, dim3(SS, HQ),  dim3(64), 0, stream, qb, cost, sint, HQ);
    hipLaunchKernelGGL(rope_apply, dim3(SS, HKV), dim3(64), 0, stream, kb, cost, sint, HKV);
    hipLaunchKernelGGL(sigmoid_k, dim3((SS * HQ * 3 + 255) / 256), dim3(256), 0, stream, g3, SS * HQ * 3);
    hipLaunchKernelGGL(cmp_kv, dim3(NCMP, HKV), dim3(128), 0, stream, kb, vb, Wck, Wcv, ckb, cvb);
    hipLaunchKernelGGL(cmp_attn, dim3(SS, HKV), dim3(128), 0, stream, qb, ckb, cvb, g3, oacc, selb);
    hipLaunchKernelGGL(sel_win, dim3(SS / TQ, HQ), dim3(256), 0, stream, qb, kb, vb, g3, selb, oacc);
    // output projection
    hipLaunchKernelGGL(conv_bf16, dim3(4096), dim3(256), 0, stream, oacc, oaccb, SS * HQ * DD / 4);
    hipLaunchKernelGGL(gemm_mfma, dim3(16, 16), dim3(256), 0, stream, oaccb, Wo_t, out, 2048, 2048, 2048);
}

// Round 3
// 897.474 us; speedup vs baseline: 3.8291x; 1.7320x over previous
//
#include <hip/hip_runtime.h>
#include <math.h>

#define SS 2048
#define HH 2048
#define HQ 16
#define HKV 4
#define GG 4
#define DD 128
#define KS 32
#define KSTRIDE 16
#define NCMP 127
#define NBLK 16
#define TOPK 8
#define WINSZ 512
#define TQ 16

typedef unsigned short u16;
typedef __bf16 bf16x8 __attribute__((ext_vector_type(8)));
typedef __bf16 bf16x4 __attribute__((ext_vector_type(4)));
typedef float f32x4 __attribute__((ext_vector_type(4)));

__device__ __forceinline__ u16 f2bf(float f) {
    __bf16 b = (__bf16)f;
    return __builtin_bit_cast(u16, b);
}

// ---------------- RoPE tables (llama3-style scaled inv freq) ----------------
__global__ void rope_tab(float* __restrict__ cost, float* __restrict__ sint) {
    int s = blockIdx.x;
    int i = threadIdx.x; // 0..63
    double inv = pow(500000.0, -(double)i / 64.0);
    double wav = 6.283185307179586476925286766559 / inv;
    double inv_s;
    if (wav > 8192.0) inv_s = inv / 8.0;
    else if (wav < 2048.0) inv_s = inv;
    else {
        double sm = (8192.0 / wav - 1.0) / 3.0;
        inv_s = (1.0 - sm) * inv / 8.0 + sm * inv;
    }
    float ang = (float)s * (float)inv_s; // reference computes angle in f32
    cost[s * 64 + i] = cosf(ang);
    sint[s * 64 + i] = sinf(ang);
}

__global__ void rope_apply(float* __restrict__ x, const float* __restrict__ cost,
                           const float* __restrict__ sint, int nh) {
    int s = blockIdx.x, h = blockIdx.y, i = threadIdx.x; // i<64
    float* p = x + ((size_t)s * nh + h) * DD;
    float c = cost[s * 64 + i], sn = sint[s * 64 + i];
    float x1 = p[i], x2 = p[i + 64];
    p[i] = x1 * c - x2 * sn;
    p[i + 64] = x2 * c + x1 * sn;
}

__global__ void sigmoid_k(float* __restrict__ x, int n) {
    int i = blockIdx.x * 256 + threadIdx.x;
    if (i < n) x[i] = 1.f / (1.f + __expf(-x[i]));
}

// ---------------- f32 -> bf16 flat convert (vec4), optional scale ----------------
__global__ void conv_bf16(const float* __restrict__ in, u16* __restrict__ out, int n4) {
    int i = blockIdx.x * 256 + threadIdx.x;
    if (i < n4) {
        float4 v = ((const float4*)in)[i];
        ushort4 o;
        o.x = f2bf(v.x); o.y = f2bf(v.y); o.z = f2bf(v.z); o.w = f2bf(v.w);
        ((ushort4*)out)[i] = o;
    }
}

__global__ void conv_scale_bf16(const float* __restrict__ in, u16* __restrict__ out,
                                int n4, float scale) {
    int i = blockIdx.x * 256 + threadIdx.x;
    if (i < n4) {
        float4 v = ((const float4*)in)[i];
        ushort4 o;
        o.x = f2bf(v.x * scale); o.y = f2bf(v.y * scale);
        o.z = f2bf(v.z * scale); o.w = f2bf(v.w * scale);
        ((ushort4*)out)[i] = o;
    }
}

// ---------------- v[s][h][d] f32 -> vt[h][d][s] bf16 ----------------
__global__ __launch_bounds__(256) void conv_vt(const float* __restrict__ v, u16* __restrict__ vt) {
    __shared__ float tile[32][33];
    int s0 = blockIdx.x * 32, d0 = blockIdx.y * 32, h = blockIdx.z;
    int tx = threadIdx.x & 31, ty = threadIdx.x >> 5;
#pragma unroll
    for (int i = 0; i < 32; i += 8)
        tile[ty + i][tx] = v[(size_t)(s0 + ty + i) * (HKV * DD) + h * DD + d0 + tx];
    __syncthreads();
#pragma unroll
    for (int i = 0; i < 32; i += 8)
        vt[(size_t)h * DD * SS + (size_t)(d0 + ty + i) * SS + s0 + tx] = f2bf(tile[tx][ty + i]);
}

// ---------------- convert + transpose: W[K][N] f32 -> Bt[Npad][K] bf16 ----------------
__global__ __launch_bounds__(256) void convT(const float* __restrict__ W, u16* __restrict__ Bt,
                                             int K, int N, int Npad) {
    __shared__ float tile[32][33];
    int bk = blockIdx.x * 32, bn = blockIdx.y * 32;
    int tx = threadIdx.x & 31, ty = threadIdx.x >> 5; // ty 0..7
#pragma unroll
    for (int i = 0; i < 32; i += 8) {
        int k = bk + ty + i, n = bn + tx;
        tile[ty + i][tx] = (n < N) ? W[(size_t)k * N + n] : 0.f;
    }
    __syncthreads();
#pragma unroll
    for (int i = 0; i < 32; i += 8) {
        int n = bn + ty + i, k = bk + tx;
        if (n < Npad) Bt[(size_t)n * K + k] = f2bf(tile[tx][ty + i]);
    }
}

// ---------------- bf16 MFMA GEMM: C[M,N] = A[M,K] @ Bt[N,K]^T ----------------
__device__ __forceinline__ void gload16(const void* g, void* l) {
    __builtin_amdgcn_global_load_lds((const __attribute__((address_space(1))) void*)g,
                                     (__attribute__((address_space(3))) void*)l, 16, 0, 0);
}

__global__ __launch_bounds__(256) void gemm_mfma(const u16* __restrict__ A,
                                                 const u16* __restrict__ Bt,
                                                 float* __restrict__ C,
                                                 int M, int N, int K) {
    __shared__ __align__(16) u16 Asm[128 * 64];
    __shared__ __align__(16) u16 Bsm[128 * 64];
    int t = threadIdx.x;
    int lane = t & 63;
    int w = t >> 6;
    int wm = w >> 1, wn = w & 1;
    int bm = blockIdx.y * 128, bn = blockIdx.x * 128;
    int lr = lane & 15, hi = lane >> 4;

    f32x4 acc[4][4] = {};
    int cflat0 = t;
    for (int k0 = 0; k0 < K; k0 += 64) {
        if (k0) __syncthreads();
#pragma unroll
        for (int i = 0; i < 4; ++i) {
            int cflat = i * 256 + cflat0;
            int m = cflat >> 3;
            int g = cflat & 7;
            int gl = g ^ (m & 7);
            unsigned lofs = (unsigned)((i * 256 + (t & ~63)) * 16);
            gload16(A + (size_t)(bm + m) * K + k0 + gl * 8, (char*)Asm + lofs);
            gload16(Bt + (size_t)(bn + m) * K + k0 + gl * 8, (char*)Bsm + lofs);
        }
        __syncthreads();
#pragma unroll
        for (int kk = 0; kk < 2; ++kk) {
            bf16x8 af[4], bf[4];
#pragma unroll
            for (int mi = 0; mi < 4; ++mi) {
                int row = wm * 64 + mi * 16 + lr;
                int g = (kk * 4 + hi) ^ (row & 7);
                af[mi] = *reinterpret_cast<const bf16x8*>(&Asm[row * 64 + g * 8]);
            }
#pragma unroll
            for (int ni = 0; ni < 4; ++ni) {
                int row = wn * 64 + ni * 16 + lr;
                int g = (kk * 4 + hi) ^ (row & 7);
                bf[ni] = *reinterpret_cast<const bf16x8*>(&Bsm[row * 64 + g * 8]);
            }
#pragma unroll
            for (int mi = 0; mi < 4; ++mi)
#pragma unroll
                for (int ni = 0; ni < 4; ++ni)
                    acc[mi][ni] = __builtin_amdgcn_mfma_f32_16x16x32_bf16(af[mi], bf[ni], acc[mi][ni], 0, 0, 0);
        }
    }
#pragma unroll
    for (int mi = 0; mi < 4; ++mi) {
#pragma unroll
        for (int ni = 0; ni < 4; ++ni) {
            int col = bn + wn * 64 + ni * 16 + lr;
            if (col < N) {
#pragma unroll
                for (int r = 0; r < 4; ++r) {
                    int row = bm + wm * 64 + mi * 16 + hi * 4 + r;
                    C[(size_t)row * N + col] = acc[mi][ni][r];
                }
            }
        }
    }
}

// ---------------- compressed K/V build ----------------
__global__ __launch_bounds__(128) void cmp_kv(const float* __restrict__ k,
                                              const float* __restrict__ v,
                                              const float* __restrict__ Wck,
                                              const float* __restrict__ Wcv,
                                              float* __restrict__ ck,
                                              float* __restrict__ cv) {
    int n = blockIdx.x, h = blockIdx.y, t = threadIdx.x; // t<128
    __shared__ float w[KS * DD];
    for (int r = 0; r < KS; ++r)
        w[r * DD + t] = k[((size_t)(n * KSTRIDE + r) * HKV + h) * DD + t];
    __syncthreads();
    {
        float acc = 0.f;
        const float* Wp = Wck + (size_t)h * KS * DD * DD + t;
        for (int f = 0; f < KS * DD; ++f) acc = fmaf(w[f], Wp[(size_t)f * DD], acc);
        ck[((size_t)h * NCMP + n) * DD + t] = acc;
    }
    __syncthreads();
    for (int r = 0; r < KS; ++r)
        w[r * DD + t] = v[((size_t)(n * KSTRIDE + r) * HKV + h) * DD + t];
    __syncthreads();
    {
        float acc = 0.f;
        const float* Wp = Wcv + (size_t)h * KS * DD * DD + t;
        for (int f = 0; f < KS * DD; ++f) acc = fmaf(w[f], Wp[(size_t)f * DD], acc);
        cv[((size_t)h * NCMP + n) * DD + t] = acc;
    }
}

// ---------------- compressed attention + block scores + top-8 ----------------
__global__ __launch_bounds__(128) void cmp_attn(const float* __restrict__ q,
                                                const float* __restrict__ ck,
                                                const float* __restrict__ cv,
                                                const float* __restrict__ gate,
                                                float* __restrict__ o_acc,
                                                unsigned int* __restrict__ sel) {
    int s = blockIdx.x, h = blockIdx.y, t = threadIdx.x; // t<128
    __shared__ float qs[GG][DD];
    __shared__ float p[GG][NCMP + 1];
    __shared__ float red[128];
    __shared__ float bsc[NBLK];
    const float scale = 0.08838834764831845f;
    for (int g = 0; g < GG; ++g)
        qs[g][t] = q[((size_t)s * HQ + h * GG + g) * DD + t] * scale;
    __syncthreads();
    int nv = (s >= 31) ? ((s - 31) >> 4) + 1 : 0;
    int n = t;
    bool act = (n < nv);
    float dots[GG] = {0.f, 0.f, 0.f, 0.f};
    if (act) {
        const float* ckp = ck + ((size_t)h * NCMP + n) * DD;
        for (int d = 0; d < DD; ++d) {
            float kv = ckp[d];
#pragma unroll
            for (int g = 0; g < GG; ++g) dots[g] = fmaf(qs[g][d], kv, dots[g]);
        }
    }
    for (int g = 0; g < GG; ++g) {
        float val = act ? dots[g] : -1e30f;
        red[t] = val; __syncthreads();
        for (int off = 64; off > 0; off >>= 1) {
            if (t < off) red[t] = fmaxf(red[t], red[t + off]);
            __syncthreads();
        }
        float m = red[0]; __syncthreads();
        float e = act ? __expf(dots[g] - m) : 0.f;
        red[t] = e; __syncthreads();
        for (int off = 64; off > 0; off >>= 1) {
            if (t < off) red[t] += red[t + off];
            __syncthreads();
        }
        float l = red[0]; __syncthreads();
        p[g][t] = (nv > 0) ? e / l : 0.f;
        __syncthreads();
    }
    {
        int d = t;
        float accs[GG] = {0.f, 0.f, 0.f, 0.f};
        const float* cvp = cv + (size_t)h * NCMP * DD + d;
        for (int nn = 0; nn < nv; ++nn) {
            float cvv = cvp[(size_t)nn * DD];
#pragma unroll
            for (int g = 0; g < GG; ++g) accs[g] = fmaf(p[g][nn], cvv, accs[g]);
        }
        for (int g = 0; g < GG; ++g) {
            float g0 = gate[((size_t)s * HQ + h * GG + g) * 3 + 0];
            o_acc[((size_t)s * HQ + h * GG + g) * DD + d] = g0 * accs[g];
        }
    }
    if (t < NBLK) {
        float b = 0.f;
        for (int g = 0; g < GG; ++g)
            for (int j = 0; j < 8; ++j) b += p[g][t * 8 + j];
        bsc[t] = b;
    }
    __syncthreads();
    if (t == 0) {
        int qblk = s >> 7;
        float sc[NBLK];
        for (int b = 0; b < NBLK; ++b) {
            bool forced = (b == 0) || (b <= qblk && b > qblk - 2);
            sc[b] = bsc[b] + (forced ? 1e9f : 0.f);
        }
        unsigned int mask = 0;
        for (int it = 0; it < TOPK; ++it) {
            int arg = 0; float best = sc[0];
            for (int b = 1; b < NBLK; ++b)
                if (sc[b] > best) { best = sc[b]; arg = b; }
            mask |= 1u << arg;
            sc[arg] = -1e38f;
        }
        sel[s * HKV + h] = mask;
    }
}

// ---------------- selected + windowed attention, MFMA flash (GQA: 4 heads/block) ----
// block = (16 q rows, h); wave w handles head hq = h*4+w. K/V staged once, shared.
// Swapped QK^T: S^T[key][q] via mfma(K_frag, Q_frag) -> lane owns one q row.
__global__ __launch_bounds__(256) void sel_win_mfma(
    const u16* __restrict__ qbf,   // [S][HQ][D] bf16, pre-scaled by 1/sqrt(D)
    const u16* __restrict__ kbf,   // [S][HKV][D] bf16
    const u16* __restrict__ vtbf,  // [HKV][D][S]  bf16 (transposed V)
    const float* __restrict__ gate,
    const unsigned int* __restrict__ sel,
    float* __restrict__ o_acc) {
    __shared__ __align__(16) u16 Ks[64 * 128];          // [key][d swizzled]
    __shared__ __align__(16) u16 Vs[128 * 64];          // [d][key swizzled]
    __shared__ __align__(16) u16 P2[4][2][16 * 64];     // per-wave, per-plane P[q][key swz]
    __shared__ unsigned int sml[16];
    int t = threadIdx.x, lane = t & 63, w = t >> 6;
    int lr = lane & 15, hi = lane >> 4;
    int s0 = blockIdx.x * 16, h = blockIdx.y;
    int hq = h * GG + w;
    int sr = s0 + lr;             // q row this lane handles in softmax role
    if (t < 16) sml[t] = sel[(s0 + t) * HKV + h];
    // Q fragments (B operand): col=q=lr, k = ks*32 + hi*8 + j
    bf16x8 qf[4];
#pragma unroll
    for (int ks = 0; ks < 4; ++ks)
        qf[ks] = *reinterpret_cast<const bf16x8*>(
            &qbf[((size_t)(s0 + lr) * HQ + hq) * DD + ks * 32 + hi * 8]);
    __syncthreads();
    unsigned mymask = sml[lr];
    unsigned orMask = 0;
#pragma unroll
    for (int i = 0; i < 16; ++i) orMask |= sml[i];
    float m_s = -1e30f, l_s = 0.f, m_w = -1e30f, l_w = 0.f;
    f32x4 Os[8] = {}, Ow[8] = {};
    int smax = s0 + 15;

    for (int kb = 0; kb * 128 <= smax; ++kb) {
        bool needSel = (orMask >> kb) & 1u;
        bool selbit = needSel && ((mymask >> kb) & 1u);
        for (int half = 0; half < 2; ++half) {
            int hst = kb * 128 + half * 64;
            if (hst > smax) break;
            bool hWin = (hst + 63 >= s0 - (WINSZ - 1));
            if (!(needSel || hWin)) continue;
            __syncthreads();   // prior iteration's PV done with Ks/Vs
            // stage K: 64 keys x 128 d (b128 in, swizzled b128 out)
#pragma unroll
            for (int i = 0; i < 4; ++i) {
                int id = i * 256 + t;
                int key = id >> 4, dq = id & 15;
                bf16x8 val = *reinterpret_cast<const bf16x8*>(
                    &kbf[((size_t)(hst + key) * HKV + h) * DD + dq * 8]);
                *reinterpret_cast<bf16x8*>(&Ks[key * 128 + ((dq ^ (key & 7)) * 8)]) = val;
            }
            // stage Vt: 128 d x 64 keys
#pragma unroll
            for (int i = 0; i < 4; ++i) {
                int id = i * 256 + t;
                int d = id >> 3, kq = id & 7;
                bf16x8 val = *reinterpret_cast<const bf16x8*>(
                    &vtbf[(size_t)h * DD * SS + (size_t)d * SS + hst + kq * 8]);
                *reinterpret_cast<bf16x8*>(&Vs[d * 64 + ((kq ^ (d & 7)) * 8)]) = val;
            }
            __syncthreads();
            // QK^T swapped: sacc[mt] holds S^T[key = mt*16+hi*4+r][q = lr]
            f32x4 sacc[4] = {};
#pragma unroll
            for (int ks = 0; ks < 4; ++ks) {
#pragma unroll
                for (int mt = 0; mt < 4; ++mt) {
                    int key = mt * 16 + lr;
                    bf16x8 kf = *reinterpret_cast<const bf16x8*>(
                        &Ks[key * 128 + (((ks * 4 + hi) ^ (key & 7)) * 8)]);
                    sacc[mt] = __builtin_amdgcn_mfma_f32_16x16x32_bf16(kf, qf[ks], sacc[mt], 0, 0, 0);
                }
            }
            // ---- sel plane softmax ----
            if (needSel) {
                float pv[4][4];
                float mx = -1e30f;
#pragma unroll
                for (int mt = 0; mt < 4; ++mt)
#pragma unroll
                    for (int r = 0; r < 4; ++r) {
                        int key = hst + mt * 16 + hi * 4 + r;
                        bool valid = selbit && (key <= sr);
                        float e = valid ? sacc[mt][r] : -1e30f;
                        pv[mt][r] = e;
                        mx = fmaxf(mx, e);
                    }
                mx = fmaxf(mx, __shfl_xor(mx, 16, 64));
                mx = fmaxf(mx, __shfl_xor(mx, 32, 64));
                float corr = 1.f;
                if (mx > -1e29f) {
                    float newm = fmaxf(m_s, mx);
                    corr = __expf(m_s - newm);
                    float lsum = 0.f;
#pragma unroll
                    for (int mt = 0; mt < 4; ++mt)
#pragma unroll
                        for (int r = 0; r < 4; ++r) {
                            float p = __expf(pv[mt][r] - newm);
                            pv[mt][r] = p;
                            lsum += p;
                        }
                    lsum += __shfl_xor(lsum, 16, 64);
                    lsum += __shfl_xor(lsum, 32, 64);
                    l_s = l_s * corr + lsum;
                    m_s = newm;
                } else {
#pragma unroll
                    for (int mt = 0; mt < 4; ++mt)
#pragma unroll
                        for (int r = 0; r < 4; ++r) pv[mt][r] = 0.f;
                }
                // rescale O rows (row q = hi*4+r lives at softmax lane lr=q)
#pragma unroll
                for (int r = 0; r < 4; ++r) {
                    float c2 = __shfl(corr, (lane >> 4) * 4 + r, 64);
#pragma unroll
                    for (int nt = 0; nt < 8; ++nt) Os[nt][r] *= c2;
                }
                // write P (bf16) to per-wave LDS, key-packed b64
#pragma unroll
                for (int mt = 0; mt < 4; ++mt) {
                    bf16x4 pk;
                    pk[0] = (__bf16)pv[mt][0]; pk[1] = (__bf16)pv[mt][1];
                    pk[2] = (__bf16)pv[mt][2]; pk[3] = (__bf16)pv[mt][3];
                    int grp = mt * 2 + (hi >> 1);
                    int idx = lr * 64 + ((grp ^ (lr & 7)) * 8) + (hi & 1) * 4;
                    *reinterpret_cast<bf16x4*>(&P2[w][0][idx]) = pk;
                }
            }
            // ---- win plane softmax ----
            if (hWin) {
                float pv[4][4];
                float mx = -1e30f;
#pragma unroll
                for (int mt = 0; mt < 4; ++mt)
#pragma unroll
                    for (int r = 0; r < 4; ++r) {
                        int key = hst + mt * 16 + hi * 4 + r;
                        bool valid = (key <= sr) && (key > sr - WINSZ);
                        float e = valid ? sacc[mt][r] : -1e30f;
                        pv[mt][r] = e;
                        mx = fmaxf(mx, e);
                    }
                mx = fmaxf(mx, __shfl_xor(mx, 16, 64));
                mx = fmaxf(mx, __shfl_xor(mx, 32, 64));
                float corr = 1.f;
                if (mx > -1e29f) {
                    float newm = fmaxf(m_w, mx);
                    corr = __expf(m_w - newm);
                    float lsum = 0.f;
#pragma unroll
                    for (int mt = 0; mt < 4; ++mt)
#pragma unroll
                        for (int r = 0; r < 4; ++r) {
                            float p = __expf(pv[mt][r] - newm);
                            pv[mt][r] = p;
                            lsum += p;
                        }
                    lsum += __shfl_xor(lsum, 16, 64);
                    lsum += __shfl_xor(lsum, 32, 64);
                    l_w = l_w * corr + lsum;
                    m_w = newm;
                } else {
#pragma unroll
                    for (int mt = 0; mt < 4; ++mt)
#pragma unroll
                        for (int r = 0; r < 4; ++r) pv[mt][r] = 0.f;
                }
#pragma unroll
                for (int r = 0; r < 4; ++r) {
                    float c2 = __shfl(corr, (lane >> 4) * 4 + r, 64);
#pragma unroll
                    for (int nt = 0; nt < 8; ++nt) Ow[nt][r] *= c2;
                }
#pragma unroll
                for (int mt = 0; mt < 4; ++mt) {
                    bf16x4 pk;
                    pk[0] = (__bf16)pv[mt][0]; pk[1] = (__bf16)pv[mt][1];
                    pk[2] = (__bf16)pv[mt][2]; pk[3] = (__bf16)pv[mt][3];
                    int grp = mt * 2 + (hi >> 1);
                    int idx = lr * 64 + ((grp ^ (lr & 7)) * 8) + (hi & 1) * 4;
                    *reinterpret_cast<bf16x4*>(&P2[w][1][idx]) = pk;
                }
            }
            __syncthreads();   // P2 visible (also keeps block in lockstep)
            // ---- PV: O[q][d] += P[q][key] * V[key][d] ----
            bf16x8 pas0, pas1, paw0, paw1;
            if (needSel) {
                pas0 = *reinterpret_cast<const bf16x8*>(&P2[w][0][lr * 64 + (((0 + hi) ^ (lr & 7)) * 8)]);
                pas1 = *reinterpret_cast<const bf16x8*>(&P2[w][0][lr * 64 + (((4 + hi) ^ (lr & 7)) * 8)]);
            }
            if (hWin) {
                paw0 = *reinterpret_cast<const bf16x8*>(&P2[w][1][lr * 64 + (((0 + hi) ^ (lr & 7)) * 8)]);
                paw1 = *reinterpret_cast<const bf16x8*>(&P2[w][1][lr * 64 + (((4 + hi) ^ (lr & 7)) * 8)]);
            }
#pragma unroll
            for (int nt = 0; nt < 8; ++nt) {
                int d = nt * 16 + lr;
                bf16x8 bv0 = *reinterpret_cast<const bf16x8*>(&Vs[d * 64 + (((0 + hi) ^ (d & 7)) * 8)]);
                bf16x8 bv1 = *reinterpret_cast<const bf16x8*>(&Vs[d * 64 + (((4 + hi) ^ (d & 7)) * 8)]);
                if (needSel) {
                    Os[nt] = __builtin_amdgcn_mfma_f32_16x16x32_bf16(pas0, bv0, Os[nt], 0, 0, 0);
                    Os[nt] = __builtin_amdgcn_mfma_f32_16x16x32_bf16(pas1, bv1, Os[nt], 0, 0, 0);
                }
                if (hWin) {
                    Ow[nt] = __builtin_amdgcn_mfma_f32_16x16x32_bf16(paw0, bv0, Ow[nt], 0, 0, 0);
                    Ow[nt] = __builtin_amdgcn_mfma_f32_16x16x32_bf16(paw1, bv1, Ow[nt], 0, 0, 0);
                }
            }
        }
    }
    // finalize: O rows q = hi*4+r, cols d = nt*16+lr
    float invls = (l_s > 0.f) ? 1.f / l_s : 0.f;
    float invlw = (l_w > 0.f) ? 1.f / l_w : 0.f;
#pragma unroll
    for (int r = 0; r < 4; ++r) {
        int q = (lane >> 4) * 4 + r;
        int srow = s0 + q;
        float a1 = gate[((size_t)srow * HQ + hq) * 3 + 1] * __shfl(invls, q, 64);
        float a2 = gate[((size_t)srow * HQ + hq) * 3 + 2] * __shfl(invlw, q, 64);
#pragma unroll
        for (int nt = 0; nt < 8; ++nt) {
            size_t idx = ((size_t)srow * HQ + hq) * DD + nt * 16 + lr;
            o_acc[idx] += a1 * Os[nt][r] + a2 * Ow[nt][r];
        }
    }
}

extern "C" void kernel_launch(void* const* d_in, const int* in_sizes, int n_in,
                              void* d_out, int out_size, void* d_ws, size_t ws_size,
                              hipStream_t stream) {
    const float* x   = (const float*)d_in[0];
    const float* Wq  = (const float*)d_in[1];
    const float* Wk  = (const float*)d_in[2];
    const float* Wv  = (const float*)d_in[3];
    const float* Wo  = (const float*)d_in[4];
    const float* Wg  = (const float*)d_in[5];
    const float* Wck = (const float*)d_in[6];
    const float* Wcv = (const float*)d_in[7];
    float* out = (float*)d_out;
    char* w = (char*)d_ws;
    float* qb   = (float*)(w + 0);          // 16 MiB
    float* kb   = (float*)(w + 16777216);   // 4 MiB
    float* vb   = (float*)(w + 20971520);   // 4 MiB
    float* g3   = (float*)(w + 25165824);
    float* ckb  = (float*)(w + 25559040);
    float* cvb  = (float*)(w + 25819136);
    unsigned int* selb = (unsigned int*)(w + 26079232);
    float* cost = (float*)(w + 26112000);
    float* sint = (float*)(w + 26636288);
    float* oacc = (float*)(w + 27160576);   // 16 MiB
    u16* xb     = (u16*)(w + 43937792);     // 8 MiB
    u16* oaccb  = (u16*)(w + 52326400);     // 8 MiB
    u16* Wq_t   = (u16*)(w + 60715008);     // 8 MiB  (reused later as qbf)
    u16* Wo_t   = (u16*)(w + 69103616);     // 8 MiB
    u16* Wk_t   = (u16*)(w + 77492224);     // 2 MiB  (reused later as kbf)
    u16* Wv_t   = (u16*)(w + 79589376);     // 2 MiB  (reused later as vtbf)
    u16* Wg_t   = (u16*)(w + 81686528);     // 0.5 MiB
    u16* qbf = Wq_t;   // S*HQ*D bf16 = 8 MiB (Wq_t dead after q projection)
    u16* kbf = Wk_t;   // S*HKV*D bf16 = 2 MiB
    u16* vtbf = Wv_t;  // HKV*D*S bf16 = 2 MiB

    hipLaunchKernelGGL(rope_tab, dim3(SS), dim3(64), 0, stream, cost, sint);
    // converts
    hipLaunchKernelGGL(conv_bf16, dim3(4096), dim3(256), 0, stream, x, xb, SS * HH / 4);
    hipLaunchKernelGGL(convT, dim3(64, 64), dim3(256), 0, stream, Wq, Wq_t, HH, 2048, 2048);
    hipLaunchKernelGGL(convT, dim3(64, 16), dim3(256), 0, stream, Wk, Wk_t, HH, 512, 512);
    hipLaunchKernelGGL(convT, dim3(64, 16), dim3(256), 0, stream, Wv, Wv_t, HH, 512, 512);
    hipLaunchKernelGGL(convT, dim3(64, 4),  dim3(256), 0, stream, Wg, Wg_t, HH, 48, 128);
    hipLaunchKernelGGL(convT, dim3(64, 64), dim3(256), 0, stream, Wo, Wo_t, HQ * DD, 2048, 2048);
    // projections (bf16 MFMA)
    hipLaunchKernelGGL(gemm_mfma, dim3(16, 16), dim3(256), 0, stream, xb, Wq_t, qb, 2048, 2048, 2048);
    hipLaunchKernelGGL(gemm_mfma, dim3(4, 16),  dim3(256), 0, stream, xb, Wk_t, kb, 2048, 512, 2048);
    hipLaunchKernelGGL(gemm_mfma, dim3(4, 16),  dim3(256), 0, stream, xb, Wv_t, vb, 2048, 512, 2048);
    hipLaunchKernelGGL(gemm_mfma, dim3(1, 16),  dim3(256), 0, stream, xb, Wg_t, g3, 2048, 48, 2048);
    hipLaunchKernelGGL(rope_apply, dim3(SS, HQ),  dim3(64), 0, stream, qb, cost, sint, HQ);
    hipLaunchKernelGGL(rope_apply, dim3(SS, HKV), dim3(64), 0, stream, kb, cost, sint, HKV);
    hipLaunchKernelGGL(sigmoid_k, dim3((SS * HQ * 3 + 255) / 256), dim3(256), 0, stream, g3, SS * HQ * 3);
    // bf16 q/k/v for MFMA attention (q pre-scaled); reuse dead weight buffers
    hipLaunchKernelGGL(conv_scale_bf16, dim3(4096), dim3(256), 0, stream, qb, qbf, SS * HQ * DD / 4, 0.08838834764831845f);
    hipLaunchKernelGGL(conv_bf16, dim3(1024), dim3(256), 0, stream, kb, kbf, SS * HKV * DD / 4);
    hipLaunchKernelGGL(conv_vt, dim3(64, 4, 4), dim3(256), 0, stream, vb, vtbf);
    // attention
    hipLaunchKernelGGL(cmp_kv, dim3(NCMP, HKV), dim3(128), 0, stream, kb, vb, Wck, Wcv, ckb, cvb);
    hipLaunchKernelGGL(cmp_attn, dim3(SS, HKV), dim3(128), 0, stream, qb, ckb, cvb, g3, oacc, selb);
    hipLaunchKernelGGL(sel_win_mfma, dim3(SS / TQ, HKV), dim3(256), 0, stream, qbf, kbf, vtbf, g3, selb, oacc);
    // output projection
    hipLaunchKernelGGL(conv_bf16, dim3(4096), dim3(256), 0, stream, oacc, oaccb, SS * HQ * DD / 4);
    hipLaunchKernelGGL(gemm_mfma, dim3(16, 16), dim3(256), 0, stream, oaccb, Wo_t, out, 2048, 2048, 2048);
}